// Round 7
// baseline (557.148 us; speedup 1.0000x reference)
//
#include <hip/hip_runtime.h>
#include <hip/hip_bf16.h>

// Sizes fixed by the problem.
#define NB 32
#define LC 1024
#define LQ 256
#define DD 512
#define NEGV (-1e10f)

typedef __attribute__((ext_vector_type(4))) float f32x4;
typedef __attribute__((ext_vector_type(8))) short s16x8;   // MFMA bf16 A/B fragment (8 bf16)
typedef __attribute__((ext_vector_type(4))) unsigned short u16x4;
typedef __attribute__((ext_vector_type(8))) unsigned short u16x8;
typedef __attribute__((ext_vector_type(4))) int i32x4;

static __device__ __forceinline__ unsigned short f2bf(float f) {
  unsigned u = __float_as_uint(f);
  u += 0x7fffu + ((u >> 16) & 1u);   // round-to-nearest-even
  return (unsigned short)(u >> 16);
}
static __device__ __forceinline__ float bf2f(unsigned short u) {
  return __uint_as_float(((unsigned)u) << 16);
}

// ---------------- kernel 0: zero rc/rq (ws is poisoned 0xAA) ----------------
__global__ __launch_bounds__(256) void k_zero(float* __restrict__ p) {
  p[blockIdx.x * 256 + threadIdx.x] = 0.f;   // grid 160 -> 40960 floats (rc+rq)
}

// ---------------- kernel 1: prep ----------------
// Per 64x64 tile: transpose -> CT/QT (bf16, d-major), row-major bf16 copies CB=bf16(C*wm), QB=bf16(Q),
// and fused rc/rq row-dots. C: 4096 tiles ; Q: 1024 tiles. grid.x = 5120.
__global__ __launch_bounds__(256) void k_prep(const float* __restrict__ Cg, const float* __restrict__ Qg,
                                              const float* __restrict__ W0,
                                              unsigned short* __restrict__ CT, unsigned short* __restrict__ QT,
                                              unsigned short* __restrict__ CB, unsigned short* __restrict__ QB,
                                              float* __restrict__ rc, float* __restrict__ rq) {
  __shared__ unsigned short tt[64][72];   // [d-local][r-local], padded stride (144B rows, 16B aligned)
  const int tid = threadIdx.x;
  const int t = blockIdx.x;
  const float* src; const float* wdot; const float* wmul; float* racc;
  unsigned short* dstT; unsigned short* dstB; int R, r0, d0; bool isC;
  if (t < 4096) {
    const int b = t >> 7, rem = t & 127;
    r0 = (rem >> 3) * 64; d0 = (rem & 7) * 64;
    src = Cg + (size_t)b * LC * DD; wdot = W0; wmul = W0 + 2 * DD;
    racc = rc + b * LC; dstT = CT + (size_t)b * DD * LC; dstB = CB + (size_t)b * LC * DD;
    R = LC; isC = true;
  } else {
    const int t2 = t - 4096;
    const int b = t2 >> 5, rem = t2 & 31;
    r0 = (rem >> 3) * 64; d0 = (rem & 7) * 64;
    src = Qg + (size_t)b * LQ * DD; wdot = W0 + DD; wmul = W0;   // wmul unused for Q
    racc = rq + b * LQ; dstT = QT + (size_t)b * DD * LQ; dstB = QB + (size_t)b * LQ * DD;
    R = LQ; isC = false;
  }
  const int cgrp = tid & 15;            // 16 threads per row, each 4 cols
  const int c = cgrp * 4;
  const f32x4 wv = *(const f32x4*)(wdot + d0 + c);
  f32x4 wmv = *(const f32x4*)(wmul + d0 + c);
  #pragma unroll
  for (int it = 0; it < 4; ++it) {
    const int rr = (tid >> 4) + 16 * it;
    f32x4 v = *(const f32x4*)(src + (size_t)(r0 + rr) * DD + d0 + c);
    // transpose into LDS (for CT/QT)
    tt[c + 0][rr] = f2bf(v[0]); tt[c + 1][rr] = f2bf(v[1]);
    tt[c + 2][rr] = f2bf(v[2]); tt[c + 3][rr] = f2bf(v[3]);
    // row-major bf16 copy (C*wm for C, raw for Q) — 8B/lane, 128B per 16-lane group
    u16x4 hb;
    if (isC) {
      #pragma unroll
      for (int e = 0; e < 4; ++e) hb[e] = f2bf(v[e] * wmv[e]);
    } else {
      #pragma unroll
      for (int e = 0; e < 4; ++e) hb[e] = f2bf(v[e]);
    }
    *(u16x4*)&dstB[(size_t)(r0 + rr) * DD + d0 + c] = hb;
    // fused dot partial
    float part = v[0]*wv[0] + v[1]*wv[1] + v[2]*wv[2] + v[3]*wv[3];
    part += __shfl_xor(part, 1); part += __shfl_xor(part, 2);
    part += __shfl_xor(part, 4); part += __shfl_xor(part, 8);
    if (cgrp == 0) atomicAdd(racc + r0 + rr, part);
  }
  __syncthreads();
  const int cp = tid >> 2, soff = (tid & 3) * 16;   // 4 threads per output row, 16 elems each
  u16x8 o0 = *(const u16x8*)&tt[cp][soff];
  u16x8 o1 = *(const u16x8*)&tt[cp][soff + 8];
  unsigned short* op = dstT + (size_t)(d0 + cp) * R + r0 + soff;
  *(u16x8*)op = o0;
  *(u16x8*)(op + 8) = o1;
}

// ---------------- kernel 2: score + fused ROW softmax (bf16 inputs) ----------------
// Tile: 64 i x 256 j (full row). 4 waves, wave w owns j in [w*64, w*64+64).
// Writes: STb bf16 [b][j][i] raw S^T (LDS-staged, coalesced), SR bf16 [b][i][j] row-softmax.
__global__ __launch_bounds__(256) void k_score_sm(const unsigned short* __restrict__ CB,
                                                  const unsigned short* __restrict__ QB,
                                                  const float* __restrict__ rc, const float* __restrict__ rq,
                                                  const int* __restrict__ q_mask,
                                                  unsigned short* __restrict__ STb, unsigned short* __restrict__ SR) {
  __shared__ unsigned short smem[18432];                               // 36864 B
  unsigned short (*sA)[40] = (unsigned short (*)[40])smem;             // [64][40]  (MFMA phase)
  unsigned short (*sB)[40] = (unsigned short (*)[40])(smem + 2560);    // [256][40] (MFMA phase)
  unsigned short (*st)[72] = (unsigned short (*)[72])smem;             // [256][72] S^T tile (epilogue)
  float* redm = (float*)smem;                                          // [64][4] max partials (after st)
  float* reds = redm + 256;                                            // [64][4] sum partials
  const int b = blockIdx.y;
  const int i0 = blockIdx.x * 64;
  const int tid = threadIdx.x, lane = tid & 63, w = tid >> 6;
  const int fr = lane & 15, fq = lane >> 4, fs = fq * 8;
  f32x4 acc[4][4];
  #pragma unroll
  for (int m = 0; m < 4; ++m)
    #pragma unroll
    for (int n = 0; n < 4; ++n)
      #pragma unroll
      for (int e = 0; e < 4; ++e) acc[m][n][e] = 0.f;

  const unsigned short* Abf = CB + ((size_t)b * LC + i0) * DD;
  const unsigned short* Bbf = QB + (size_t)b * LQ * DD;
  const int arow = tid >> 2, acol = (tid & 3) * 8;

  for (int k = 0; k < DD; k += 32) {
    __syncthreads();
    *(u16x8*)&sA[arow][acol] = *(const u16x8*)(Abf + (size_t)arow * DD + k + acol);
    #pragma unroll
    for (int it = 0; it < 4; ++it) {
      const int brow = arow + 64 * it;
      *(u16x8*)&sB[brow][acol] = *(const u16x8*)(Bbf + (size_t)brow * DD + k + acol);
    }
    __syncthreads();
    s16x8 af[4], bfv[4];
    #pragma unroll
    for (int m = 0; m < 4; ++m) af[m] = *(const s16x8*)&sA[m * 16 + fr][fs];
    #pragma unroll
    for (int n = 0; n < 4; ++n) bfv[n] = *(const s16x8*)&sB[w * 64 + n * 16 + fr][fs];
    #pragma unroll
    for (int m = 0; m < 4; ++m)
      #pragma unroll
      for (int n = 0; n < 4; ++n)
        acc[m][n] = __builtin_amdgcn_mfma_f32_16x16x32_bf16(af[m], bfv[n], acc[m][n], 0, 0, 0);
  }

  // ---- epilogue ----
  f32x4 rc4[4];
  #pragma unroll
  for (int m = 0; m < 4; ++m) rc4[m] = *(const f32x4*)(rc + b * LC + i0 + m * 16 + fq * 4);
  float rqv[4]; int qm[4];
  #pragma unroll
  for (int n = 0; n < 4; ++n) {
    const int j = w * 64 + n * 16 + fr;
    rqv[n] = rq[b * LQ + j];
    qm[n] = q_mask[b * LQ + j];
  }
  __syncthreads();   // sA/sB dead; st phase begins
  #pragma unroll
  for (int m = 0; m < 4; ++m)
    #pragma unroll
    for (int n = 0; n < 4; ++n) {
      f32x4 v = acc[m][n];
      #pragma unroll
      for (int e = 0; e < 4; ++e) v[e] += rc4[m][e] + rqv[n];
      u16x4 hv;
      #pragma unroll
      for (int e = 0; e < 4; ++e) hv[e] = f2bf(v[e]);
      *(u16x4*)&st[w * 64 + n * 16 + fr][m * 16 + fq * 4] = hv;   // S^T tile in LDS
      if (qm[n] == 1) {
        #pragma unroll
        for (int e = 0; e < 4; ++e) v[e] = NEGV;
      }
      acc[m][n] = v;
    }
  __syncthreads();
  // coop write STb: 256 rows x 64 i, 128B contiguous per 8-lane group
  {
    const int jr = tid >> 3, off = (tid & 7) * 8;
    #pragma unroll
    for (int p = 0; p < 8; ++p) {
      const int j = p * 32 + (jr & 31);
      *(u16x8*)&STb[((size_t)b * LQ + j) * LC + i0 + off] = *(const u16x8*)&st[j][off];
    }
  }
  __syncthreads();   // st dead; redm/reds region safe
  // per-row (i) max across n and fr lanes, then across 4 waves via LDS
  f32x4 mx[4];
  #pragma unroll
  for (int m = 0; m < 4; ++m) {
    mx[m] = acc[m][0];
    #pragma unroll
    for (int n = 1; n < 4; ++n)
      #pragma unroll
      for (int e = 0; e < 4; ++e) mx[m][e] = fmaxf(mx[m][e], acc[m][n][e]);
    #pragma unroll
    for (int e = 0; e < 4; ++e) {
      float x = mx[m][e];
      x = fmaxf(x, __shfl_xor(x, 1)); x = fmaxf(x, __shfl_xor(x, 2));
      x = fmaxf(x, __shfl_xor(x, 4)); x = fmaxf(x, __shfl_xor(x, 8));
      mx[m][e] = x;
    }
  }
  if (fr == 0) {
    #pragma unroll
    for (int m = 0; m < 4; ++m)
      #pragma unroll
      for (int e = 0; e < 4; ++e) redm[(m * 16 + fq * 4 + e) * 4 + w] = mx[m][e];
  }
  __syncthreads();
  f32x4 M[4];
  #pragma unroll
  for (int m = 0; m < 4; ++m)
    #pragma unroll
    for (int e = 0; e < 4; ++e) {
      f32x4 r = *(const f32x4*)&redm[(m * 16 + fq * 4 + e) * 4];
      M[m][e] = fmaxf(fmaxf(r[0], r[1]), fmaxf(r[2], r[3]));
    }
  f32x4 sm[4];
  #pragma unroll
  for (int m = 0; m < 4; ++m) {
    #pragma unroll
    for (int e = 0; e < 4; ++e) sm[m][e] = 0.f;
    #pragma unroll
    for (int n = 0; n < 4; ++n) {
      f32x4 p;
      #pragma unroll
      for (int e = 0; e < 4; ++e) { p[e] = __expf(acc[m][n][e] - M[m][e]); sm[m][e] += p[e]; }
      acc[m][n] = p;
    }
    #pragma unroll
    for (int e = 0; e < 4; ++e) {
      float x = sm[m][e];
      x += __shfl_xor(x, 1); x += __shfl_xor(x, 2);
      x += __shfl_xor(x, 4); x += __shfl_xor(x, 8);
      sm[m][e] = x;
    }
  }
  if (fr == 0) {
    #pragma unroll
    for (int m = 0; m < 4; ++m)
      #pragma unroll
      for (int e = 0; e < 4; ++e) reds[(m * 16 + fq * 4 + e) * 4 + w] = sm[m][e];
  }
  __syncthreads();
  #pragma unroll
  for (int m = 0; m < 4; ++m) {
    f32x4 inv;
    #pragma unroll
    for (int e = 0; e < 4; ++e) {
      f32x4 r = *(const f32x4*)&reds[(m * 16 + fq * 4 + e) * 4];
      inv[e] = 1.0f / (r[0] + r[1] + r[2] + r[3]);
    }
    #pragma unroll
    for (int n = 0; n < 4; ++n) {
      const int j = w * 64 + n * 16 + fr;
      #pragma unroll
      for (int e = 0; e < 4; ++e)
        SR[((size_t)b * LC + i0 + m * 16 + fq * 4 + e) * LQ + j] = f2bf(acc[m][n][e] * inv[e]);
    }
  }
}

// ---------------- kernel 3: column softmax on STb rows -> SC bf16 [b][j][i] ----------------
__global__ __launch_bounds__(256) void k_colsm(const unsigned short* __restrict__ STb, const int* __restrict__ c_mask,
                                               unsigned short* __restrict__ SC) {
  const int lane = threadIdx.x & 63, wid = threadIdx.x >> 6;
  const int r = blockIdx.x * 4 + wid;          // r = b*LQ + j
  const int b = r >> 8;
  const unsigned short* row = STb + (size_t)r * LC;
  const int* cm = c_mask + b * LC;
  float v[16];
  #pragma unroll
  for (int sgm = 0; sgm < 2; ++sgm) {
    const int base = sgm * 512 + lane * 8;
    u16x8 h = *(const u16x8*)(row + base);
    i32x4 m0 = *(const i32x4*)(cm + base);
    i32x4 m1 = *(const i32x4*)(cm + base + 4);
    #pragma unroll
    for (int e = 0; e < 4; ++e) {
      v[sgm * 8 + e]     = (m0[e] == 1) ? NEGV : bf2f(h[e]);
      v[sgm * 8 + 4 + e] = (m1[e] == 1) ? NEGV : bf2f(h[4 + e]);
    }
  }
  float m = v[0];
  #pragma unroll
  for (int e = 1; e < 16; ++e) m = fmaxf(m, v[e]);
  #pragma unroll
  for (int o = 32; o >= 1; o >>= 1) m = fmaxf(m, __shfl_xor(m, o));
  float s = 0.f;
  #pragma unroll
  for (int e = 0; e < 16; ++e) { v[e] = __expf(v[e] - m); s += v[e]; }
  #pragma unroll
  for (int o = 32; o >= 1; o >>= 1) s += __shfl_xor(s, o);
  const float inv = 1.0f / s;
  unsigned short* orow = SC + (size_t)r * LC;
  #pragma unroll
  for (int sgm = 0; sgm < 2; ++sgm) {
    u16x8 hv;
    #pragma unroll
    for (int e = 0; e < 8; ++e) hv[e] = f2bf(v[sgm * 8 + e] * inv);
    *(u16x8*)(orow + sgm * 512 + lane * 8) = hv;
  }
}

// ---------------- kernel 4: T^T[b,d,j] = sum_i CT[b,d,i] * SC[b,j,i]  (A=CT rows, B=SC rows) ----------------
__global__ __launch_bounds__(256) void k_tgemm(const unsigned short* __restrict__ SC, const unsigned short* __restrict__ CT,
                                               unsigned short* __restrict__ TT) {
  __shared__ unsigned short sA[128][40];   // [d][k=i]
  __shared__ unsigned short sB[128][40];   // [j][k=i]
  const int b = blockIdx.z;
  const int j0 = blockIdx.x * 128;   // gridDim.x = 2
  const int d0 = blockIdx.y * 128;   // gridDim.y = 4
  const int tid = threadIdx.x, lane = tid & 63, wid = tid >> 6;
  const int wr = wid >> 1, wc = wid & 1;
  const int fr = lane & 15, fq = lane >> 4, fs = fq * 8;
  f32x4 acc[4][4];
  #pragma unroll
  for (int m = 0; m < 4; ++m)
    #pragma unroll
    for (int n = 0; n < 4; ++n)
      #pragma unroll
      for (int e = 0; e < 4; ++e) acc[m][n][e] = 0.f;
  const int srow = tid >> 1, scol = (tid & 1) * 16;
  const unsigned short* Ab = CT + ((size_t)b * DD + d0) * LC;   // A rows = d
  const unsigned short* Bb = SC + ((size_t)b * LQ + j0) * LC;   // B rows = j

  for (int k = 0; k < LC; k += 32) {
    __syncthreads();
    const unsigned short* ap = Ab + (size_t)srow * LC + k + scol;
    const unsigned short* bp = Bb + (size_t)srow * LC + k + scol;
    *(u16x8*)&sA[srow][scol]     = *(const u16x8*)ap;
    *(u16x8*)&sA[srow][scol + 8] = *(const u16x8*)(ap + 8);
    *(u16x8*)&sB[srow][scol]     = *(const u16x8*)bp;
    *(u16x8*)&sB[srow][scol + 8] = *(const u16x8*)(bp + 8);
    __syncthreads();
    s16x8 af[4], bfv[4];
    #pragma unroll
    for (int m = 0; m < 4; ++m) af[m] = *(const s16x8*)&sA[wr * 64 + m * 16 + fr][fs];
    #pragma unroll
    for (int n = 0; n < 4; ++n) bfv[n] = *(const s16x8*)&sB[wc * 64 + n * 16 + fr][fs];
    #pragma unroll
    for (int m = 0; m < 4; ++m)
      #pragma unroll
      for (int n = 0; n < 4; ++n)
        acc[m][n] = __builtin_amdgcn_mfma_f32_16x16x32_bf16(af[m], bfv[n], acc[m][n], 0, 0, 0);
  }
  // store: d = M-dim row, j = N-dim col (fr-contiguous -> 32B chunks)
  #pragma unroll
  for (int m = 0; m < 4; ++m)
    #pragma unroll
    for (int n = 0; n < 4; ++n) {
      const int j = j0 + wc * 64 + n * 16 + fr;
      #pragma unroll
      for (int e = 0; e < 4; ++e) {
        const int d = d0 + wr * 64 + m * 16 + fq * 4 + e;
        TT[((size_t)b * DD + d) * LQ + j] = f2bf(acc[m][n][e]);
      }
    }
}

// ---------------- kernel 5: A/Bt = SR @ [QT|TT]^T, fused output epilogue ----------------
__global__ __launch_bounds__(256) void k_out(const unsigned short* __restrict__ SR, const unsigned short* __restrict__ QT,
                                             const unsigned short* __restrict__ TT, const float* __restrict__ Cg,
                                             float* __restrict__ out) {
  __shared__ unsigned short sA[128][40];
  __shared__ unsigned short sB[128][40];
  const int b = blockIdx.z;
  const int i0 = blockIdx.x * 128;   // 8 tiles
  const int n0 = blockIdx.y * 128;   // 8 tiles over virtual N=1024 ([Q | T])
  const bool qpath = (n0 < 512);
  const unsigned short* Bb = qpath ? (QT + ((size_t)b * DD + n0) * LQ)
                                   : (TT + ((size_t)b * DD + n0 - 512) * LQ);
  const unsigned short* Ab = SR + ((size_t)b * LC + i0) * LQ;
  const int tid = threadIdx.x, lane = tid & 63, wid = tid >> 6;
  const int wr = wid >> 1, wc = wid & 1;
  const int fr = lane & 15, fq = lane >> 4, fs = fq * 8;
  f32x4 acc[4][4];
  #pragma unroll
  for (int m = 0; m < 4; ++m)
    #pragma unroll
    for (int n = 0; n < 4; ++n)
      #pragma unroll
      for (int e = 0; e < 4; ++e) acc[m][n][e] = 0.f;
  const int srow = tid >> 1, scol = (tid & 1) * 16;

  for (int k = 0; k < LQ; k += 32) {
    __syncthreads();
    const unsigned short* ap = Ab + (size_t)srow * LQ + k + scol;
    const unsigned short* bp = Bb + (size_t)srow * LQ + k + scol;
    *(u16x8*)&sA[srow][scol]     = *(const u16x8*)ap;
    *(u16x8*)&sA[srow][scol + 8] = *(const u16x8*)(ap + 8);
    *(u16x8*)&sB[srow][scol]     = *(const u16x8*)bp;
    *(u16x8*)&sB[srow][scol + 8] = *(const u16x8*)(bp + 8);
    __syncthreads();
    s16x8 af[4], bfv[4];
    #pragma unroll
    for (int m = 0; m < 4; ++m) af[m] = *(const s16x8*)&sA[wr * 64 + m * 16 + fr][fs];
    #pragma unroll
    for (int n = 0; n < 4; ++n) bfv[n] = *(const s16x8*)&sB[wc * 64 + n * 16 + fr][fs];
    #pragma unroll
    for (int m = 0; m < 4; ++m)
      #pragma unroll
      for (int n = 0; n < 4; ++n)
        acc[m][n] = __builtin_amdgcn_mfma_f32_16x16x32_bf16(af[m], bfv[n], acc[m][n], 0, 0, 0);
  }

  #pragma unroll
  for (int m = 0; m < 4; ++m)
    #pragma unroll
    for (int n = 0; n < 4; ++n) {
      const int i = i0 + wr * 64 + m * 16 + fq * 4;
      const int dl = wc * 64 + n * 16 + fr;
      #pragma unroll
      for (int e = 0; e < 4; ++e) {
        const size_t ri = (size_t)b * LC + i + e;
        const size_t orow = ri * (4 * DD);
        const float a = acc[m][n][e];
        if (qpath) {
          const int d = n0 + dl;
          const float cv = Cg[ri * DD + d];
          out[orow + d] = cv;                 // segment 0: C
          out[orow + DD + d] = a;             // segment 1: A
          out[orow + 2 * DD + d] = cv * a;    // segment 2: C*A
        } else {
          const int d = n0 - 512 + dl;
          const float cv = Cg[ri * DD + d];
          out[orow + 3 * DD + d] = cv * a;    // segment 3: C*Bt
        }
      }
    }
}

extern "C" void kernel_launch(void* const* d_in, const int* in_sizes, int n_in,
                              void* d_out, int out_size, void* d_ws, size_t ws_size,
                              hipStream_t stream) {
  const float* Cg     = (const float*)d_in[0];
  const float* Qg     = (const float*)d_in[1];
  const float* W0     = (const float*)d_in[2];
  const int*   c_mask = (const int*)d_in[3];
  const int*   q_mask = (const int*)d_in[4];
  float* out = (float*)d_out;
  char* ws = (char*)d_ws;
  (void)in_sizes; (void)n_in; (void)out_size; (void)ws_size;

  // Workspace layout (bytes); total = 142,770,176 (~136 MB)
  float*          rc  = (float*)(ws + 0);                   // 131072
  float*          rq  = (float*)(ws + 131072);              // 32768
  unsigned short* CT  = (unsigned short*)(ws + 163840);     // 33554432  bf16 [b][d][i]   raw C^T
  unsigned short* QT  = (unsigned short*)(ws + 33718272);   // 8388608   bf16 [b][d][j]   raw Q^T
  unsigned short* STb = (unsigned short*)(ws + 42106880);   // 16777216  bf16 [b][j][i]   raw S^T
  unsigned short* SR  = (unsigned short*)(ws + 58884096);   // 16777216  bf16 [b][i][j]   row-softmax
  unsigned short* SC  = (unsigned short*)(ws + 75661312);   // 16777216  bf16 [b][j][i]   col-softmax
  unsigned short* TT  = (unsigned short*)(ws + 92438528);   // 8388608   bf16 [b][d][j]   T^T
  unsigned short* CB  = (unsigned short*)(ws + 100827136);  // 33554432  bf16 [b][i][d]   C*wm
  unsigned short* QB  = (unsigned short*)(ws + 134381568);  // 8388608   bf16 [b][j][d]   Q

  k_zero    <<<dim3(160),        dim3(256), 0, stream>>>((float*)ws);
  k_prep    <<<dim3(5120),       dim3(256), 0, stream>>>(Cg, Qg, W0, CT, QT, CB, QB, rc, rq);
  k_score_sm<<<dim3(16, 32),     dim3(256), 0, stream>>>(CB, QB, rc, rq, q_mask, STb, SR);
  k_colsm   <<<dim3(2048),       dim3(256), 0, stream>>>(STb, c_mask, SC);
  k_tgemm   <<<dim3(2, 4, NB),   dim3(256), 0, stream>>>(SC, CT, TT);
  k_out     <<<dim3(8, 8, NB),   dim3(256), 0, stream>>>(SR, QT, TT, Cg, out);
}